// Round 1
// 6131.055 us; speedup vs baseline: 1.0715x; 1.0715x over previous
//
#include <hip/hip_runtime.h>

// HighwayLayerDiscrete: 256-step recurrent highway net, batch 64, units 1024.
// Phase P = t*4+p: p0: h=lrelu(y@w_y + xproj[t]); p1/p2: h=lrelu(h@w_h[l]+b_h[l]);
// p3: y += h@w_out + b_out; out[:,t,:]=y.
//
// R8 = R7 (6.57 ms) + handoff-protocol fixes (geometry/compute unchanged):
//  1. PER-PRODUCER FLAGS: flags[rg*32+cg], single-writer plain relaxed sc1
//     store of P+1 (R7's 32x fetch_add on ONE word serialized RMWs at the LLC
//     bank and made the poller queue behind them). Consumer poll = wave0
//     32-lane vector load + __all — one LLC trip checks all 32 producers.
//  2. DEFERRED out STORE: p3's HBM out-write now issues AFTER the flag post,
//     so its ~1k-cy HBM ack drains under the next phase's poll/stage instead
//     of inside the tail waitcnt(0) on the serial chain.
//  3. FINALIZE-OPERAND PREFETCH: xp (p0, LLC-cold!), b_h (p1/2), ybuf+b_out
//     (p3) loads issue right after the poll barrier -> latency hides under
//     A-stage + compute instead of sitting on the producer tail.
// Carried invariants: 256 coop blocks x 512 thr (R4: >256 blocks silently
// fails); no cross-WG split-K (R2/R3: partial exchange = ~1-2M LLC trans =
// wall); no fences ever (R1: buffer_wbl2/inv = 66 ms); cross-WG data via
// relaxed agent-scope atomics (sc1 at LLC); release = waitcnt0+barrier+flag;
// acquire = poll + barrier + asm clobber; LDS skew injective (R5 bug);
// a_s/red2 alias => keep compute->red-write barrier.

constexpr int B = 64, T = 256, U = 1024, E = 512;
constexpr int BU = B * U;     // 65536
constexpr int APITCH = 1156;  // A-row pitch (1024 + 36-skew; ==4 mod 8)

#define LRELU(v) ((v) > 0.f ? (v) : 0.2f * (v))

using f4 = float __attribute__((ext_vector_type(4)));

__device__ __forceinline__ unsigned long long llc_load64(const float* p) {
  return __hip_atomic_load((const unsigned long long*)p, __ATOMIC_RELAXED,
                           __HIP_MEMORY_SCOPE_AGENT);
}
__device__ __forceinline__ void llc_store(float* p, float v) {
  __hip_atomic_store(p, v, __ATOMIC_RELAXED, __HIP_MEMORY_SCOPE_AGENT);
}
__device__ __forceinline__ unsigned llc_flag(const unsigned* p) {
  return __hip_atomic_load(p, __ATOMIC_RELAXED, __HIP_MEMORY_SCOPE_AGENT);
}
__device__ __forceinline__ void llc_post(unsigned* p, unsigned v) {
  __hip_atomic_store(p, v, __ATOMIC_RELAXED, __HIP_MEMORY_SCOPE_AGENT);
}

// ---------------- init: zero flags, y0 into slot1 and ybuf ----------------
__global__ void k_init(float* __restrict__ slot1, float* __restrict__ ybuf,
                       const float* __restrict__ h0,
                       unsigned* __restrict__ flags) {
  int tid = blockIdx.x * 256 + threadIdx.x;
  if (tid < 512) flags[tid] = 0u;
  if (tid < BU) {
    float v = h0[tid & (U - 1)];
    slot1[tid] = v;
    ybuf[tid] = v;
  }
}

// ------- xproj[t*64+n][u] = emb[x[n][t]] @ w_x + b_in (R2/R3-proven) -------
__global__ __launch_bounds__(256) void k_xproj(
    const int* __restrict__ x, const float* __restrict__ emb,
    const float* __restrict__ w_x, const float* __restrict__ b_in,
    float* __restrict__ xp) {
  __shared__ float a_s[64][36];
  __shared__ float w_s[32][64];
  __shared__ int idxs[64];
  const int tid = threadIdx.x;
  const int m0 = blockIdx.x * 64;
  const int c0 = blockIdx.y * 64;
  if (tid < 64) {
    int m = m0 + tid;
    idxs[tid] = x[(m & 63) * T + (m >> 6)];  // x[n][t], row m = t*64+n
  }
  __syncthreads();
  const int rq = tid >> 4, cq = tid & 15;
  float acc[4][4] = {};
  for (int k0 = 0; k0 < E; k0 += 32) {
#pragma unroll
    for (int rep = 0; rep < 8; ++rep) {
      int e = rep * 256 + tid;
      int r = e >> 5, k = e & 31;
      a_s[r][k] = emb[(size_t)idxs[r] * E + k0 + k];
    }
#pragma unroll
    for (int rep = 0; rep < 2; ++rep) {
      int e = rep * 256 + tid;
      int kr = e >> 4, q = e & 15;
      *(float4*)&w_s[kr][4 * q] =
          *(const float4*)(w_x + (size_t)(k0 + kr) * U + c0 + 4 * q);
    }
    __syncthreads();
#pragma unroll
    for (int kc = 0; kc < 32; kc += 4) {
      float4 a4[4], w4[4];
#pragma unroll
      for (int i = 0; i < 4; ++i) a4[i] = *(const float4*)&a_s[4 * rq + i][kc];
#pragma unroll
      for (int kk = 0; kk < 4; ++kk)
        w4[kk] = *(const float4*)&w_s[kc + kk][4 * cq];
#pragma unroll
      for (int i = 0; i < 4; ++i) {
        const float av[4] = {a4[i].x, a4[i].y, a4[i].z, a4[i].w};
#pragma unroll
        for (int kk = 0; kk < 4; ++kk) {
          acc[i][0] += av[kk] * w4[kk].x;
          acc[i][1] += av[kk] * w4[kk].y;
          acc[i][2] += av[kk] * w4[kk].z;
          acc[i][3] += av[kk] * w4[kk].w;
        }
      }
    }
    __syncthreads();
  }
  const float4 bb = *(const float4*)(b_in + c0 + 4 * cq);
  const float bv[4] = {bb.x, bb.y, bb.z, bb.w};
#pragma unroll
  for (int i = 0; i < 4; ++i) {
    float4 o;
    o.x = acc[i][0] + bv[0];
    o.y = acc[i][1] + bv[1];
    o.z = acc[i][2] + bv[2];
    o.w = acc[i][3] + bv[3];
    *(float4*)(xp + (size_t)(m0 + 4 * rq + i) * U + c0 + 4 * cq) = o;
  }
}

// ---------------- sequential pipeline ----------------
// 256 WGs = 8 rg x 32 cg (XCD = cg&7, L2-affine). Thread (s,ri,ci): K-slice
// [32s,32s+32), rows [4ri,4ri+4) of 8, cols [4ci,4ci+4) of 32. Partials ->
// red2[s][out] pitch 264. a_s (8 x 1156 = 9248 floats) ALIASES red2 (32 x
// 264 = 8448) — barriers order A-read < red-write < red-read < next A-write.
__global__ __launch_bounds__(512, 2) void k_seq(
    const float* __restrict__ xp, const float* __restrict__ w_y,
    const float* __restrict__ w_h, const float* __restrict__ b_h,
    const float* __restrict__ w_out, const float* __restrict__ b_out,
    float* __restrict__ out, float* __restrict__ slots,
    float* __restrict__ ybuf, unsigned* __restrict__ flags) {
  __shared__ float smem[8 * APITCH];  // 9248 floats = 36992 B
  float* const a_s = smem;   // [row][36*(k>>5) + (k&31)] (injective skew)
  float* const red2 = smem;  // [s][out], pitch 264 (alias — see barriers)
  const int tid = threadIdx.x;
  const int cg = blockIdx.x & 31, rg = blockIdx.x >> 5;
  const int l = tid & 63;
  const int ci = l & 7, ri = (l >> 3) & 1;
  const int s = (tid >> 6) * 4 + ((l >> 4) & 3);
  const int cb = 4 * ci, r0 = 4 * ri, k0 = 32 * s;
  // finalize-lane coords (valid for tid < 256)
  const int frow = 8 * rg + (tid >> 5);
  const int fu = 32 * cg + (tid & 31);

  // W base selector for phase P
  auto wbase = [&](int P) -> const float* {
    const int p = P & 3;
    const float* Wsrc = (p == 0)   ? w_y
                        : (p == 3) ? w_out
                                   : w_h + (size_t)(p - 1) * U * U;
    return Wsrc + (size_t)k0 * U + 32 * cg + cb;
  };
  // ---- W prefetch for P=0 (static addresses -> latency off critical path) --
  f4 wreg[32];  // W[k0+j][cb..cb+4), j=0..31 -> 128 VGPRs
  {
    const float* wp = wbase(0);
#pragma unroll
    for (int j = 0; j < 32; ++j) wreg[j] = *(const f4*)(wp + (size_t)j * U);
  }

  for (int P = 0; P < 4 * T; ++P) {
    const int t = P >> 2, p = P & 3;
    const float* Asrc =
        slots + (size_t)((P + 1) & 1) * BU + (size_t)(8 * rg) * U;
    float* slotw = slots + (size_t)(P & 1) * BU;
    // ---- 1. poll: wave0 vector-reads all 32 per-producer flags at once ----
    if (P > 0) {
      if (tid < 64) {
        const unsigned tgt = (unsigned)P;
        const unsigned* fp = &flags[rg * 32 + (l & 31)];
        while (!__all(llc_flag(fp) >= tgt)) __builtin_amdgcn_s_sleep(1);
      }
      __syncthreads();
      asm volatile("" ::: "memory");
    }
    // ---- 1b. finalize-operand prefetch (off the producer tail) ----
    float preA = 0.f, preB = 0.f;
    if (tid < 256) {
      if (p == 0)
        preA = xp[((size_t)t * B + frow) * U + fu];
      else if (p < 3)
        preA = b_h[(p - 1) * U + fu];
      else {
        preA = ybuf[(size_t)frow * U + fu];  // WG-private: plain ok
        preB = b_out[fu];
      }
    }
    // ---- 2. stage A: 8 rows x 1024, 8B sc1 loads -> single b128 LDS write --
#pragma unroll
    for (int rep = 0; rep < 4; ++rep) {
      int idx4 = 512 * rep + tid;  // f4 index in [0,2048)
      int row = idx4 >> 8, kq = idx4 & 255, k = 4 * kq;
      const float* pa = Asrc + (size_t)row * U + k;
      unsigned long long v0 = llc_load64(pa);
      unsigned long long v1 = llc_load64(pa + 2);
      f4 v;
      ((unsigned long long*)&v)[0] = v0;
      ((unsigned long long*)&v)[1] = v1;
      *(f4*)&a_s[row * APITCH + 36 * (k >> 5) + (k & 31)] = v;
    }
    __syncthreads();
    // ---- 3. main: 4x4x(K=32) tile; A from LDS, W from registers ----
    f4 acc[4];
#pragma unroll
    for (int i = 0; i < 4; ++i) acc[i] = (f4){0.f, 0.f, 0.f, 0.f};
    {
      const int abase = r0 * APITCH + 36 * s;  // 36*(k0>>5) = 36s
#pragma unroll
      for (int q = 0; q < 8; ++q) {
        const int ai = abase + 4 * q;
        f4 a0 = *(const f4*)&a_s[ai];
        f4 a1 = *(const f4*)&a_s[ai + APITCH];
        f4 a2 = *(const f4*)&a_s[ai + 2 * APITCH];
        f4 a3 = *(const f4*)&a_s[ai + 3 * APITCH];
        const f4 w0 = wreg[4 * q], w1 = wreg[4 * q + 1];
        const f4 w2 = wreg[4 * q + 2], w3 = wreg[4 * q + 3];
        acc[0] += a0.x * w0 + a0.y * w1 + a0.z * w2 + a0.w * w3;
        acc[1] += a1.x * w0 + a1.y * w1 + a1.z * w2 + a1.w * w3;
        acc[2] += a2.x * w0 + a2.y * w1 + a2.z * w2 + a2.w * w3;
        acc[3] += a3.x * w0 + a3.y * w1 + a3.z * w2 + a3.w * w3;
      }
    }
    __syncthreads();  // all a_s reads done -> safe to alias-write red2
    // ---- 4. write partials red2[s*264 + out], b128 ----
#pragma unroll
    for (int i = 0; i < 4; ++i)
      *(f4*)&red2[s * 264 + (r0 + i) * 32 + cb] = acc[i];
    __syncthreads();
    // ---- 5. finalize: 256 threads, sum 32 partials, bias+act, store ----
    float yn = 0.f;
    bool wout = false;
    if (tid < 256) {
      float sum = 0.f;
#pragma unroll
      for (int z = 0; z < 32; ++z) sum += red2[z * 264 + tid];
      const size_t yi = (size_t)frow * U + fu;
      if (p < 3) {
        float v = sum + preA;  // p0: xp (has b_in folded); p1/2: b_h
        llc_store(slotw + yi, LRELU(v));
      } else {
        yn = preA + preB + sum;  // ybuf + b_out + h@w_out
        ybuf[yi] = yn;
        llc_store(slotw + yi, yn);  // y is next p0's A
        wout = true;                // out store deferred past the post
      }
    }
    // ---- 6. drain + release ----
    asm volatile("" ::: "memory");
    __builtin_amdgcn_s_waitcnt(0);
    __syncthreads();
    // ---- 7. post own flag (plain sc1 store, single writer -> no RMW) ----
    if (tid == 0) llc_post(&flags[rg * 32 + cg], (unsigned)(P + 1));
    // ---- 8. deferred out store (HBM ack drains off-chain) ----
    if (wout) out[((size_t)frow * T + t) * U + fu] = yn;
    // ---- 9. W prefetch for P+1 (L2 traffic overlaps poll + A-stage) ----
    if (P < 4 * T - 1) {
      const float* wp = wbase(P + 1);
#pragma unroll
      for (int j = 0; j < 32; ++j) wreg[j] = *(const f4*)(wp + (size_t)j * U);
    }
  }
}

extern "C" void kernel_launch(void* const* d_in, const int* in_sizes, int n_in,
                              void* d_out, int out_size, void* d_ws,
                              size_t ws_size, hipStream_t stream) {
  const int* x = (const int*)d_in[0];
  const float* emb = (const float*)d_in[1];
  const float* w_y = (const float*)d_in[2];
  const float* w_x = (const float*)d_in[3];
  const float* b_in = (const float*)d_in[4];
  const float* w_h = (const float*)d_in[5];
  const float* b_h = (const float*)d_in[6];
  const float* w_out = (const float*)d_in[7];
  const float* b_out = (const float*)d_in[8];
  const float* h0 = (const float*)d_in[9];
  float* out = (float*)d_out;

  // workspace (floats): xproj | slots[2] | ybuf | flags
  float* ws = (float*)d_ws;
  float* xpb = ws;                         // T*B*U
  float* slots = xpb + (size_t)T * B * U;  // 2*BU
  float* ybuf = slots + 2 * (size_t)BU;    // BU
  unsigned* flags = (unsigned*)(ybuf + (size_t)BU);  // 512 uints

  k_init<<<256, 256, 0, stream>>>(slots + (size_t)BU, ybuf, h0, flags);
  dim3 g1(256, 16);
  k_xproj<<<g1, 256, 0, stream>>>(x, emb, w_x, b_in, xpb);

  void* args[] = {&xpb,   &w_y, &w_h,   &b_h,  &w_out,
                  &b_out, &out, &slots, &ybuf, &flags};
  hipLaunchCooperativeKernel((void*)k_seq, dim3(256), dim3(512), args, 0u,
                             stream);
}

// Round 2
// 5176.250 us; speedup vs baseline: 1.2692x; 1.1845x over previous
//
#include <hip/hip_runtime.h>

// HighwayLayerDiscrete: 256-step recurrent highway net, batch 64, units 1024.
// Phase P = t*4+p: p0: h=lrelu(y@w_y + xproj[t]); p1/p2: h=lrelu(h@w_h[l]+b_h[l]);
// p3: y += h@w_out + b_out; out[:,t,:]=y.
//
// R9 = R8 (6.13 ms) + W-bandwidth + A-stage fixes:
//  1. K-RETILE: thread = (s' in [0,64), ci in [0,8)) owns K-slice of 16 and
//     ALL 8 rows. W fragment (16 rows x 4 cols) is now UNIQUE per thread ->
//     W prefetch traffic halves: 256->128 KB/WG/phase (8->4 MB/XCD at 4.3
//     TB/s L2 = ~0.9 us, now fully hidden under poll+stage; R8's 1.9 us
//     partially extended every phase). wreg 128->64 VGPRs. Reduction 32->64
//     partials (4-way ILP).
//  2. A-stage via inline-asm global_load_dwordx4 sc1 (16B, was 2x8B atomic
//     loads) -> half the LLC requests; explicit s_waitcnt vmcnt(0) before
//     LDS writes.
//  3. A-read order rotated by cg so the 32 identical consumer streams of a
//     row-group don't collide on the same LLC lines cycle-by-cycle.
//  4. a_s / red2 DE-ALIASED (104.6 KB LDS, 1 WG/CU) -> compute->red-write
//     barrier removed (4 barriers/phase).
// Carried invariants: 256 coop blocks x 512 thr (R4: >256 blocks silently
// fails); no cross-WG split-K (R2/R3: partial exchange = ~1-2M LLC trans =
// wall); no fences ever (R1: buffer_wbl2/inv = 66 ms); cross-WG data via
// relaxed agent-scope ops (sc1 at LLC); release = waitcnt0+barrier+flag;
// acquire = wave0 32-lane poll + barrier + asm clobber; per-producer flags
// (R8); deferred out store (R8); finalize-operand prefetch (R8); LDS skew
// injective (R5 bug).

constexpr int B = 64, T = 256, U = 1024, E = 512;
constexpr int BU = B * U;     // 65536
constexpr int APITCH = 1156;  // A-row pitch (1024 + 36-skew; ==4 mod 8)
constexpr int RPITCH = 264;   // red2 slice pitch (256 + 8)

#define LRELU(v) ((v) > 0.f ? (v) : 0.2f * (v))

using f4 = float __attribute__((ext_vector_type(4)));

__device__ __forceinline__ void llc_store(float* p, float v) {
  __hip_atomic_store(p, v, __ATOMIC_RELAXED, __HIP_MEMORY_SCOPE_AGENT);
}
__device__ __forceinline__ unsigned llc_flag(const unsigned* p) {
  return __hip_atomic_load(p, __ATOMIC_RELAXED, __HIP_MEMORY_SCOPE_AGENT);
}
__device__ __forceinline__ void llc_post(unsigned* p, unsigned v) {
  __hip_atomic_store(p, v, __ATOMIC_RELAXED, __HIP_MEMORY_SCOPE_AGENT);
}

// ---------------- init: zero flags, y0 into slot1 and ybuf ----------------
__global__ void k_init(float* __restrict__ slot1, float* __restrict__ ybuf,
                       const float* __restrict__ h0,
                       unsigned* __restrict__ flags) {
  int tid = blockIdx.x * 256 + threadIdx.x;
  if (tid < 512) flags[tid] = 0u;
  if (tid < BU) {
    float v = h0[tid & (U - 1)];
    slot1[tid] = v;
    ybuf[tid] = v;
  }
}

// ------- xproj[t*64+n][u] = emb[x[n][t]] @ w_x + b_in (R2/R3-proven) -------
__global__ __launch_bounds__(256) void k_xproj(
    const int* __restrict__ x, const float* __restrict__ emb,
    const float* __restrict__ w_x, const float* __restrict__ b_in,
    float* __restrict__ xp) {
  __shared__ float a_s[64][36];
  __shared__ float w_s[32][64];
  __shared__ int idxs[64];
  const int tid = threadIdx.x;
  const int m0 = blockIdx.x * 64;
  const int c0 = blockIdx.y * 64;
  if (tid < 64) {
    int m = m0 + tid;
    idxs[tid] = x[(m & 63) * T + (m >> 6)];  // x[n][t], row m = t*64+n
  }
  __syncthreads();
  const int rq = tid >> 4, cq = tid & 15;
  float acc[4][4] = {};
  for (int k0 = 0; k0 < E; k0 += 32) {
#pragma unroll
    for (int rep = 0; rep < 8; ++rep) {
      int e = rep * 256 + tid;
      int r = e >> 5, k = e & 31;
      a_s[r][k] = emb[(size_t)idxs[r] * E + k0 + k];
    }
#pragma unroll
    for (int rep = 0; rep < 2; ++rep) {
      int e = rep * 256 + tid;
      int kr = e >> 4, q = e & 15;
      *(float4*)&w_s[kr][4 * q] =
          *(const float4*)(w_x + (size_t)(k0 + kr) * U + c0 + 4 * q);
    }
    __syncthreads();
#pragma unroll
    for (int kc = 0; kc < 32; kc += 4) {
      float4 a4[4], w4[4];
#pragma unroll
      for (int i = 0; i < 4; ++i) a4[i] = *(const float4*)&a_s[4 * rq + i][kc];
#pragma unroll
      for (int kk = 0; kk < 4; ++kk)
        w4[kk] = *(const float4*)&w_s[kc + kk][4 * cq];
#pragma unroll
      for (int i = 0; i < 4; ++i) {
        const float av[4] = {a4[i].x, a4[i].y, a4[i].z, a4[i].w};
#pragma unroll
        for (int kk = 0; kk < 4; ++kk) {
          acc[i][0] += av[kk] * w4[kk].x;
          acc[i][1] += av[kk] * w4[kk].y;
          acc[i][2] += av[kk] * w4[kk].z;
          acc[i][3] += av[kk] * w4[kk].w;
        }
      }
    }
    __syncthreads();
  }
  const float4 bb = *(const float4*)(b_in + c0 + 4 * cq);
  const float bv[4] = {bb.x, bb.y, bb.z, bb.w};
#pragma unroll
  for (int i = 0; i < 4; ++i) {
    float4 o;
    o.x = acc[i][0] + bv[0];
    o.y = acc[i][1] + bv[1];
    o.z = acc[i][2] + bv[2];
    o.w = acc[i][3] + bv[3];
    *(float4*)(xp + (size_t)(m0 + 4 * rq + i) * U + c0 + 4 * cq) = o;
  }
}

// ---------------- sequential pipeline ----------------
// 256 WGs = 8 rg x 32 cg (XCD = cg&7, L2-affine). Thread (s',ci): K-slice
// [16s',16s'+16), ALL 8 rows, cols [4ci,4ci+4) of 32. Partials ->
// red2[s'][out] pitch 264 (de-aliased from a_s).
__global__ __launch_bounds__(512, 2) void k_seq(
    const float* __restrict__ xp, const float* __restrict__ w_y,
    const float* __restrict__ w_h, const float* __restrict__ b_h,
    const float* __restrict__ w_out, const float* __restrict__ b_out,
    float* __restrict__ out, float* __restrict__ slots,
    float* __restrict__ ybuf, unsigned* __restrict__ flags) {
  __shared__ float a_s[8 * APITCH];     // 9248 floats
  __shared__ float red2[64 * RPITCH];   // 16896 floats (total 104576 B)
  const int tid = threadIdx.x;
  const int cg = blockIdx.x & 31, rg = blockIdx.x >> 5;
  const int w = tid >> 6, l = tid & 63;
  const int ci = l & 7;
  const int sp = w * 8 + (l >> 3);  // s' in [0,64)
  const int cb = 4 * ci, k0 = 16 * sp;
  const int abase_k = 36 * (sp >> 1) + 16 * (sp & 1);  // skewed k0 offset
  // finalize-lane coords (valid for tid < 256)
  const int frow = 8 * rg + (tid >> 5);
  const int fu = 32 * cg + (tid & 31);
  // staging coords: row set {tb, tb+2, tb+4, tb+6}, rotated k start
  const int tb = tid >> 8;  // 0 or 1
  const int kq = ((tid & 255) + 8 * cg) & 255;  // f4-unit index, cg-rotated
  const int lofs = 36 * (kq >> 3) + ((4 * kq) & 31);  // skewed LDS k-offset

  // W base selector for phase P
  auto wbase = [&](int P) -> const float* {
    const int p = P & 3;
    const float* Wsrc = (p == 0)   ? w_y
                        : (p == 3) ? w_out
                                   : w_h + (size_t)(p - 1) * U * U;
    return Wsrc + (size_t)k0 * U + 32 * cg + cb;
  };
  // ---- W prefetch for P=0: 16 rows x 4 cols, UNIQUE per thread ----
  f4 wreg[16];  // 64 VGPRs
  {
    const float* wp = wbase(0);
#pragma unroll
    for (int j = 0; j < 16; ++j) wreg[j] = *(const f4*)(wp + (size_t)j * U);
  }

  for (int P = 0; P < 4 * T; ++P) {
    const int t = P >> 2, p = P & 3;
    const float* Asrc =
        slots + (size_t)((P + 1) & 1) * BU + (size_t)(8 * rg) * U;
    float* slotw = slots + (size_t)(P & 1) * BU;
    // ---- 1. poll: wave0 vector-reads all 32 per-producer flags at once ----
    if (P > 0) {
      if (tid < 64) {
        const unsigned tgt = (unsigned)P;
        const unsigned* fp = &flags[rg * 32 + (l & 31)];
        while (!__all(llc_flag(fp) >= tgt)) __builtin_amdgcn_s_sleep(1);
      }
      __syncthreads();
      asm volatile("" ::: "memory");
    }
    // ---- 1b. finalize-operand prefetch (off the producer tail) ----
    float preA = 0.f, preB = 0.f;
    if (tid < 256) {
      if (p == 0)
        preA = xp[((size_t)t * B + frow) * U + fu];
      else if (p < 3)
        preA = b_h[(p - 1) * U + fu];
      else {
        preA = ybuf[(size_t)frow * U + fu];  // WG-private: plain ok
        preB = b_out[fu];
      }
    }
    // ---- 2. stage A: 8 rows x 1024 floats, b128 sc1 loads, cg-rotated ----
    {
      const float* pb = Asrc + 4 * kq;
      f4 av0, av1, av2, av3;
      asm volatile("global_load_dwordx4 %0, %1, off sc1"
                   : "=v"(av0) : "v"(pb + (size_t)tb * U));
      asm volatile("global_load_dwordx4 %0, %1, off sc1"
                   : "=v"(av1) : "v"(pb + (size_t)(tb + 2) * U));
      asm volatile("global_load_dwordx4 %0, %1, off sc1"
                   : "=v"(av2) : "v"(pb + (size_t)(tb + 4) * U));
      asm volatile("global_load_dwordx4 %0, %1, off sc1"
                   : "=v"(av3) : "v"(pb + (size_t)(tb + 6) * U));
      asm volatile("s_waitcnt vmcnt(0)" ::: "memory");
      *(f4*)&a_s[(tb + 0) * APITCH + lofs] = av0;
      *(f4*)&a_s[(tb + 2) * APITCH + lofs] = av1;
      *(f4*)&a_s[(tb + 4) * APITCH + lofs] = av2;
      *(f4*)&a_s[(tb + 6) * APITCH + lofs] = av3;
    }
    __syncthreads();
    // ---- 3. main: 8x4x(K=16) tile; A from LDS (8-lane bcast), W from regs --
    f4 acc[8];
#pragma unroll
    for (int r = 0; r < 8; ++r) acc[r] = (f4){0.f, 0.f, 0.f, 0.f};
#pragma unroll
    for (int q = 0; q < 4; ++q) {
      const f4 w0 = wreg[4 * q], w1 = wreg[4 * q + 1];
      const f4 w2 = wreg[4 * q + 2], w3 = wreg[4 * q + 3];
      const int ab = abase_k + 4 * q;
#pragma unroll
      for (int r = 0; r < 8; ++r) {
        f4 a = *(const f4*)&a_s[r * APITCH + ab];
        acc[r] += a.x * w0 + a.y * w1 + a.z * w2 + a.w * w3;
      }
    }
    // ---- 4. write partials red2[sp][r*32+cb] (no barrier: de-aliased) ----
#pragma unroll
    for (int r = 0; r < 8; ++r)
      *(f4*)&red2[sp * RPITCH + r * 32 + cb] = acc[r];
    __syncthreads();
    // ---- 5. finalize: 256 threads, sum 64 partials (4-way ILP), store ----
    float yn = 0.f;
    bool wout = false;
    if (tid < 256) {
      float s0 = 0.f, s1 = 0.f, s2 = 0.f, s3 = 0.f;
#pragma unroll
      for (int z = 0; z < 64; z += 4) {
        s0 += red2[(z + 0) * RPITCH + tid];
        s1 += red2[(z + 1) * RPITCH + tid];
        s2 += red2[(z + 2) * RPITCH + tid];
        s3 += red2[(z + 3) * RPITCH + tid];
      }
      const float sum = (s0 + s1) + (s2 + s3);
      const size_t yi = (size_t)frow * U + fu;
      if (p < 3) {
        float v = sum + preA;  // p0: xp (has b_in folded); p1/2: b_h
        llc_store(slotw + yi, LRELU(v));
      } else {
        yn = preA + preB + sum;  // ybuf + b_out + h@w_out
        ybuf[yi] = yn;
        llc_store(slotw + yi, yn);  // y is next p0's A
        wout = true;                // out store deferred past the post
      }
    }
    // ---- 6. drain + release ----
    asm volatile("" ::: "memory");
    __builtin_amdgcn_s_waitcnt(0);
    __syncthreads();
    // ---- 7. post own flag (plain sc1 store, single writer -> no RMW) ----
    if (tid == 0) llc_post(&flags[rg * 32 + cg], (unsigned)(P + 1));
    // ---- 8. deferred out store (HBM ack drains off-chain) ----
    if (wout) out[((size_t)frow * T + t) * U + fu] = yn;
    // ---- 9. W prefetch for P+1 (L2 traffic overlaps poll + A-stage) ----
    if (P < 4 * T - 1) {
      const float* wp = wbase(P + 1);
#pragma unroll
      for (int j = 0; j < 16; ++j) wreg[j] = *(const f4*)(wp + (size_t)j * U);
    }
  }
}

extern "C" void kernel_launch(void* const* d_in, const int* in_sizes, int n_in,
                              void* d_out, int out_size, void* d_ws,
                              size_t ws_size, hipStream_t stream) {
  const int* x = (const int*)d_in[0];
  const float* emb = (const float*)d_in[1];
  const float* w_y = (const float*)d_in[2];
  const float* w_x = (const float*)d_in[3];
  const float* b_in = (const float*)d_in[4];
  const float* w_h = (const float*)d_in[5];
  const float* b_h = (const float*)d_in[6];
  const float* w_out = (const float*)d_in[7];
  const float* b_out = (const float*)d_in[8];
  const float* h0 = (const float*)d_in[9];
  float* out = (float*)d_out;

  // workspace (floats): xproj | slots[2] | ybuf | flags
  float* ws = (float*)d_ws;
  float* xpb = ws;                         // T*B*U
  float* slots = xpb + (size_t)T * B * U;  // 2*BU
  float* ybuf = slots + 2 * (size_t)BU;    // BU
  unsigned* flags = (unsigned*)(ybuf + (size_t)BU);  // 512 uints

  k_init<<<256, 256, 0, stream>>>(slots + (size_t)BU, ybuf, h0, flags);
  dim3 g1(256, 16);
  k_xproj<<<g1, 256, 0, stream>>>(x, emb, w_x, b_in, xpb);

  void* args[] = {&xpb,   &w_y, &w_h,   &b_h,  &w_out,
                  &b_out, &out, &slots, &ybuf, &flags};
  hipLaunchCooperativeKernel((void*)k_seq, dim3(256), dim3(512), args, 0u,
                             stream);
}

// Round 4
// 5140.752 us; speedup vs baseline: 1.2780x; 1.0069x over previous
//
#include <hip/hip_runtime.h>

// HighwayLayerDiscrete: 256-step recurrent highway net, batch 64, units 1024.
// Phase P = t*4+p: p0: h=lrelu(y@w_y + xproj[t]); p1/p2: h=lrelu(h@w_h[l]+b_h[l]);
// p3: y += h@w_out + b_out; out[:,t,:]=y.
//
// R11 = R9 (5.18 ms, PASSED) + ONE change: cg-grouped XCD mapping for W
// L2-residency. R10 post-mortem: crashed/hung — it wrote ticket counters
// past the established 512-uint flags footprint and made CORRECTNESS depend
// on perfect XCD grouping (sc0-only exchange => one stale line = deadlock).
// Both reverted: back to the R9 sc1 (device-scope) protocol everywhere.
//
// W-BANDWIDTH THEORY: each WG reads 128 KB of W per phase -> 32 MB/phase
// chip-wide, ~33 GB total, all from LLC (HBM FETCH is only 1.1 GB). At
// 5.05 us/phase that's 6.3 TB/s sustained LLC streaming — the R9 limiter.
// Duplication factor 8: W slab [1024 x 32cg] is re-read by all 8 rgs.
// FIX: map cg = (bid&7)*4 + ((bid>>3)&3), rg = bid>>5. Under the default
// round-robin bid->XCD dispatch each XCD hosts cg in {4x..4x+3} x all rg:
// W working set/XCD = 4 slabs x 4 matrices x 128 KB = 2 MB < 4 MB L2 ->
// W L2-resident (plain cacheable loads; W is read-only so trivially
// coherent). PURE HEURISTIC: if the mapping differs, W just misses L2 —
// results stay correct because ALL exchange stays sc1 device-scope (G16).
// A-stage sc1 loads bypass L2 -> no W eviction. out/xp/ybuf traffic per
// XCD is KB-scale — negligible pollution.
// Carried invariants: 256 coop blocks x 512 thr (R4: >256 silently fails);
// no cross-WG split-K (R2/R3); no explicit cache fences (R1: wbl2/inv =
// 66 ms); release = waitcnt0+barrier+flag; acquire = wave0 32-lane poll +
// barrier + clobber; per-producer flags, 512-uint footprint (R8/R10 lesson);
// deferred out store (R8); finalize-operand prefetch (R8); K-retile 64x16,
// unique W frags, de-aliased red2 (R9); LDS skew injective (R5 bug).

constexpr int B = 64, T = 256, U = 1024, E = 512;
constexpr int BU = B * U;     // 65536
constexpr int APITCH = 1156;  // A-row pitch (1024 + 36-skew; ==4 mod 8)
constexpr int RPITCH = 264;   // red2 slice pitch (256 + 8)

#define LRELU(v) ((v) > 0.f ? (v) : 0.2f * (v))

using f4 = float __attribute__((ext_vector_type(4)));

__device__ __forceinline__ void llc_store(float* p, float v) {
  __hip_atomic_store(p, v, __ATOMIC_RELAXED, __HIP_MEMORY_SCOPE_AGENT);
}
__device__ __forceinline__ unsigned llc_flag(const unsigned* p) {
  return __hip_atomic_load(p, __ATOMIC_RELAXED, __HIP_MEMORY_SCOPE_AGENT);
}
__device__ __forceinline__ void llc_post(unsigned* p, unsigned v) {
  __hip_atomic_store(p, v, __ATOMIC_RELAXED, __HIP_MEMORY_SCOPE_AGENT);
}

// ---------------- init: zero flags, y0 into slot1 and ybuf ----------------
__global__ void k_init(float* __restrict__ slot1, float* __restrict__ ybuf,
                       const float* __restrict__ h0,
                       unsigned* __restrict__ flags) {
  int tid = blockIdx.x * 256 + threadIdx.x;
  if (tid < 512) flags[tid] = 0u;
  if (tid < BU) {
    float v = h0[tid & (U - 1)];
    slot1[tid] = v;
    ybuf[tid] = v;
  }
}

// ------- xproj[t*64+n][u] = emb[x[n][t]] @ w_x + b_in (R2/R3-proven) -------
__global__ __launch_bounds__(256) void k_xproj(
    const int* __restrict__ x, const float* __restrict__ emb,
    const float* __restrict__ w_x, const float* __restrict__ b_in,
    float* __restrict__ xp) {
  __shared__ float a_s[64][36];
  __shared__ float w_s[32][64];
  __shared__ int idxs[64];
  const int tid = threadIdx.x;
  const int m0 = blockIdx.x * 64;
  const int c0 = blockIdx.y * 64;
  if (tid < 64) {
    int m = m0 + tid;
    idxs[tid] = x[(m & 63) * T + (m >> 6)];  // x[n][t], row m = t*64+n
  }
  __syncthreads();
  const int rq = tid >> 4, cq = tid & 15;
  float acc[4][4] = {};
  for (int k0 = 0; k0 < E; k0 += 32) {
#pragma unroll
    for (int rep = 0; rep < 8; ++rep) {
      int e = rep * 256 + tid;
      int r = e >> 5, k = e & 31;
      a_s[r][k] = emb[(size_t)idxs[r] * E + k0 + k];
    }
#pragma unroll
    for (int rep = 0; rep < 2; ++rep) {
      int e = rep * 256 + tid;
      int kr = e >> 4, q = e & 15;
      *(float4*)&w_s[kr][4 * q] =
          *(const float4*)(w_x + (size_t)(k0 + kr) * U + c0 + 4 * q);
    }
    __syncthreads();
#pragma unroll
    for (int kc = 0; kc < 32; kc += 4) {
      float4 a4[4], w4[4];
#pragma unroll
      for (int i = 0; i < 4; ++i) a4[i] = *(const float4*)&a_s[4 * rq + i][kc];
#pragma unroll
      for (int kk = 0; kk < 4; ++kk)
        w4[kk] = *(const float4*)&w_s[kc + kk][4 * cq];
#pragma unroll
      for (int i = 0; i < 4; ++i) {
        const float av[4] = {a4[i].x, a4[i].y, a4[i].z, a4[i].w};
#pragma unroll
        for (int kk = 0; kk < 4; ++kk) {
          acc[i][0] += av[kk] * w4[kk].x;
          acc[i][1] += av[kk] * w4[kk].y;
          acc[i][2] += av[kk] * w4[kk].z;
          acc[i][3] += av[kk] * w4[kk].w;
        }
      }
    }
    __syncthreads();
  }
  const float4 bb = *(const float4*)(b_in + c0 + 4 * cq);
  const float bv[4] = {bb.x, bb.y, bb.z, bb.w};
#pragma unroll
  for (int i = 0; i < 4; ++i) {
    float4 o;
    o.x = acc[i][0] + bv[0];
    o.y = acc[i][1] + bv[1];
    o.z = acc[i][2] + bv[2];
    o.w = acc[i][3] + bv[3];
    *(float4*)(xp + (size_t)(m0 + 4 * rq + i) * U + c0 + 4 * cq) = o;
  }
}

// ---------------- sequential pipeline ----------------
// 256 WGs. cg = (bid&7)*4 + ((bid>>3)&3), rg = bid>>5  (bijective; under
// round-robin bid->XCD each XCD sees 4 cg values x all 8 rg -> 2MB W set).
// Thread (s',ci): K-slice [16s',16s'+16), ALL 8 rows, cols [4ci,4ci+4) of 32.
// Partials -> red2[s'][out] pitch 264 (de-aliased from a_s).
__global__ __launch_bounds__(512, 2) void k_seq(
    const float* __restrict__ xp, const float* __restrict__ w_y,
    const float* __restrict__ w_h, const float* __restrict__ b_h,
    const float* __restrict__ w_out, const float* __restrict__ b_out,
    float* __restrict__ out, float* __restrict__ slots,
    float* __restrict__ ybuf, unsigned* __restrict__ flags) {
  __shared__ float a_s[8 * APITCH];    // 9248 floats
  __shared__ float red2[64 * RPITCH];  // 16896 floats (total 104576 B)
  const int tid = threadIdx.x;
  const int bid = blockIdx.x;
  const int cg = ((bid & 7) << 2) | ((bid >> 3) & 3);  // XCD-affine W slab
  const int rg = bid >> 5;
  const int w = tid >> 6, l = tid & 63;
  const int ci = l & 7;
  const int sp = w * 8 + (l >> 3);  // s' in [0,64)
  const int cb = 4 * ci, k0 = 16 * sp;
  const int abase_k = 36 * (sp >> 1) + 16 * (sp & 1);  // skewed k0 offset
  // finalize-lane coords (valid for tid < 256)
  const int frow = 8 * rg + (tid >> 5);
  const int fu = 32 * cg + (tid & 31);
  // staging coords: row set {tb, tb+2, tb+4, tb+6}, rotated k start
  const int tb = tid >> 8;                      // 0 or 1
  const int kq = ((tid & 255) + 8 * cg) & 255;  // f4-unit index, cg-rotated
  const int lofs = 36 * (kq >> 3) + ((4 * kq) & 31);  // skewed LDS k-offset

  // W base selector for phase P
  auto wbase = [&](int P) -> const float* {
    const int p = P & 3;
    const float* Wsrc = (p == 0)   ? w_y
                        : (p == 3) ? w_out
                                   : w_h + (size_t)(p - 1) * U * U;
    return Wsrc + (size_t)k0 * U + 32 * cg + cb;
  };
  // ---- W prefetch for P=0: 16 rows x 4 cols, UNIQUE per thread ----
  f4 wreg[16];  // 64 VGPRs
  {
    const float* wp = wbase(0);
#pragma unroll
    for (int j = 0; j < 16; ++j) wreg[j] = *(const f4*)(wp + (size_t)j * U);
  }

  for (int P = 0; P < 4 * T; ++P) {
    const int t = P >> 2, p = P & 3;
    const float* Asrc =
        slots + (size_t)((P + 1) & 1) * BU + (size_t)(8 * rg) * U;
    float* slotw = slots + (size_t)(P & 1) * BU;
    // ---- 1. poll: wave0 vector-reads all 32 per-producer flags at once ----
    if (P > 0) {
      if (tid < 64) {
        const unsigned tgt = (unsigned)P;
        const unsigned* fp = &flags[rg * 32 + (l & 31)];
        while (!__all(llc_flag(fp) >= tgt)) __builtin_amdgcn_s_sleep(1);
      }
      __syncthreads();
      asm volatile("" ::: "memory");
    }
    // ---- 1b. finalize-operand prefetch (off the producer tail) ----
    float preA = 0.f, preB = 0.f;
    if (tid < 256) {
      if (p == 0)
        preA = xp[((size_t)t * B + frow) * U + fu];
      else if (p < 3)
        preA = b_h[(p - 1) * U + fu];
      else {
        preA = ybuf[(size_t)frow * U + fu];  // WG-private: plain ok
        preB = b_out[fu];
      }
    }
    // ---- 2. stage A: 8 rows x 1024 floats, b128 sc1 loads, cg-rotated ----
    {
      const float* pb = Asrc + 4 * kq;
      f4 av0, av1, av2, av3;
      asm volatile("global_load_dwordx4 %0, %1, off sc1"
                   : "=v"(av0)
                   : "v"(pb + (size_t)tb * U));
      asm volatile("global_load_dwordx4 %0, %1, off sc1"
                   : "=v"(av1)
                   : "v"(pb + (size_t)(tb + 2) * U));
      asm volatile("global_load_dwordx4 %0, %1, off sc1"
                   : "=v"(av2)
                   : "v"(pb + (size_t)(tb + 4) * U));
      asm volatile("global_load_dwordx4 %0, %1, off sc1"
                   : "=v"(av3)
                   : "v"(pb + (size_t)(tb + 6) * U));
      asm volatile("s_waitcnt vmcnt(0)" ::: "memory");
      *(f4*)&a_s[(tb + 0) * APITCH + lofs] = av0;
      *(f4*)&a_s[(tb + 2) * APITCH + lofs] = av1;
      *(f4*)&a_s[(tb + 4) * APITCH + lofs] = av2;
      *(f4*)&a_s[(tb + 6) * APITCH + lofs] = av3;
    }
    __syncthreads();
    // ---- 3. main: 8x4x(K=16) tile; A from LDS (8-lane bcast), W from regs --
    f4 acc[8];
#pragma unroll
    for (int r = 0; r < 8; ++r) acc[r] = (f4){0.f, 0.f, 0.f, 0.f};
#pragma unroll
    for (int q = 0; q < 4; ++q) {
      const f4 w0 = wreg[4 * q], w1 = wreg[4 * q + 1];
      const f4 w2 = wreg[4 * q + 2], w3 = wreg[4 * q + 3];
      const int ab = abase_k + 4 * q;
#pragma unroll
      for (int r = 0; r < 8; ++r) {
        f4 a = *(const f4*)&a_s[r * APITCH + ab];
        acc[r] += a.x * w0 + a.y * w1 + a.z * w2 + a.w * w3;
      }
    }
    // ---- 4. write partials red2[sp][r*32+cb] (no barrier: de-aliased) ----
#pragma unroll
    for (int r = 0; r < 8; ++r)
      *(f4*)&red2[sp * RPITCH + r * 32 + cb] = acc[r];
    __syncthreads();
    // ---- 5. finalize: 256 threads, sum 64 partials (4-way ILP), store ----
    float yn = 0.f;
    bool wout = false;
    if (tid < 256) {
      float s0 = 0.f, s1 = 0.f, s2 = 0.f, s3 = 0.f;
#pragma unroll
      for (int z = 0; z < 64; z += 4) {
        s0 += red2[(z + 0) * RPITCH + tid];
        s1 += red2[(z + 1) * RPITCH + tid];
        s2 += red2[(z + 2) * RPITCH + tid];
        s3 += red2[(z + 3) * RPITCH + tid];
      }
      const float sum = (s0 + s1) + (s2 + s3);
      const size_t yi = (size_t)frow * U + fu;
      if (p < 3) {
        float v = sum + preA;  // p0: xp (has b_in folded); p1/2: b_h
        llc_store(slotw + yi, LRELU(v));
      } else {
        yn = preA + preB + sum;  // ybuf + b_out + h@w_out
        ybuf[yi] = yn;
        llc_store(slotw + yi, yn);  // y is next p0's A
        wout = true;                // out store deferred past the post
      }
    }
    // ---- 6. drain + release ----
    asm volatile("" ::: "memory");
    __builtin_amdgcn_s_waitcnt(0);
    __syncthreads();
    // ---- 7. post own flag (plain sc1 store, single writer -> no RMW) ----
    if (tid == 0) llc_post(&flags[rg * 32 + cg], (unsigned)(P + 1));
    // ---- 8. deferred out store (HBM ack drains off-chain) ----
    if (wout) out[((size_t)frow * T + t) * U + fu] = yn;
    // ---- 9. W prefetch for P+1 (L2-resident -> ~200cy, overlaps poll) ----
    if (P < 4 * T - 1) {
      const float* wp = wbase(P + 1);
#pragma unroll
      for (int j = 0; j < 16; ++j) wreg[j] = *(const f4*)(wp + (size_t)j * U);
    }
  }
}

extern "C" void kernel_launch(void* const* d_in, const int* in_sizes, int n_in,
                              void* d_out, int out_size, void* d_ws,
                              size_t ws_size, hipStream_t stream) {
  const int* x = (const int*)d_in[0];
  const float* emb = (const float*)d_in[1];
  const float* w_y = (const float*)d_in[2];
  const float* w_x = (const float*)d_in[3];
  const float* b_in = (const float*)d_in[4];
  const float* w_h = (const float*)d_in[5];
  const float* b_h = (const float*)d_in[6];
  const float* w_out = (const float*)d_in[7];
  const float* b_out = (const float*)d_in[8];
  const float* h0 = (const float*)d_in[9];
  float* out = (float*)d_out;

  // workspace (floats): xproj | slots[2] | ybuf | flags
  float* ws = (float*)d_ws;
  float* xpb = ws;                         // T*B*U
  float* slots = xpb + (size_t)T * B * U;  // 2*BU
  float* ybuf = slots + 2 * (size_t)BU;    // BU
  unsigned* flags = (unsigned*)(ybuf + (size_t)BU);  // 512 uints

  k_init<<<256, 256, 0, stream>>>(slots + (size_t)BU, ybuf, h0, flags);
  dim3 g1(256, 16);
  k_xproj<<<g1, 256, 0, stream>>>(x, emb, w_x, b_in, xpb);

  void* args[] = {&xpb,   &w_y, &w_h,   &b_h,  &w_out,
                  &b_out, &out, &slots, &ybuf, &flags};
  hipLaunchCooperativeKernel((void*)k_seq, dim3(256), dim3(512), args, 0u,
                             stream);
}

// Round 5
// 4826.757 us; speedup vs baseline: 1.3611x; 1.0651x over previous
//
#include <hip/hip_runtime.h>

// HighwayLayerDiscrete: 256-step recurrent highway net, batch 64, units 1024.
// Reference step t: h1=lrelu(y@w_y+xp[t]); h2=lrelu(h1@Wh0+b0); h3=lrelu(h2@Wh1+b1);
// y += h3@w_out + b_out; out[:,t,:]=y.
//
// R12 = R11 (5.14 ms) + PHASE-COUNT CUT 4->3 via W2 = w_out@w_y:
//   u_{t+1} := y_t@w_y  ==  u_t + h3_t@W2 + c2   (c2 = b_out@w_y)
// so p0's matmul vanishes: h1_{t+1} = lrelu(u + xp[t+1]) is elementwise,
// fused into ph3's finalize. 1024 -> 768 serialized sync phases. The y
// update (h3@w_out, needed only for out[]) runs OFF-CHAIN after the flag
// post, hiding in the next phase's poll slack. u and y live in ONE register
// per finalize lane (ybuf dead). W2 is computed ONCE per WG into persistent
// registers (w2reg[16] = the thread's exact fragment) by an in-kernel
// prologue GEMM (~130 us, redundant x8 across rg — no workspace growth;
// R10 lesson: don't touch the ws footprint, don't make correctness depend
// on XCD mapping). R11 post-mortem: W was ALREADY L2-resident under the
// natural mapping (cg ≡ XCD mod 8) — W BW is not the limiter; the serial
// phase count is. Keep R11's cg mapping (harmless, keeps W L2-resident).
// Carried invariants: 256 coop blocks x 512 thr (R4: >256 silently fails);
// no cross-WG split-K (R2/R3); no cache fences (R1); sc1 device-scope
// exchange only (R10: sc0 cross-WG = deadlock); release =
// waitcnt0+barrier+flag; acquire = wave0 32-lane poll + barrier + clobber;
// per-producer flags, 512-uint footprint (R8); finalize-operand prefetch
// (R8); K-retile 64x16, unique W frags, de-aliased red2 (R9); LDS skew
// injective (R5).

constexpr int B = 64, T = 256, U = 1024, E = 512;
constexpr int BU = B * U;     // 65536
constexpr int APITCH = 1156;  // A-row pitch (1024 + 36-skew; ==4 mod 8)
constexpr int RPITCH = 264;   // red2 slice pitch (256 + 8)
constexpr int WOPITCH = 9;    // prologue w_out_s pitch (odd -> 4-way max)

#define LRELU(v) ((v) > 0.f ? (v) : 0.2f * (v))

using f4 = float __attribute__((ext_vector_type(4)));

__device__ __forceinline__ void llc_store(float* p, float v) {
  __hip_atomic_store(p, v, __ATOMIC_RELAXED, __HIP_MEMORY_SCOPE_AGENT);
}
__device__ __forceinline__ unsigned llc_flag(const unsigned* p) {
  return __hip_atomic_load(p, __ATOMIC_RELAXED, __HIP_MEMORY_SCOPE_AGENT);
}
__device__ __forceinline__ void llc_post(unsigned* p, unsigned v) {
  __hip_atomic_store(p, v, __ATOMIC_RELAXED, __HIP_MEMORY_SCOPE_AGENT);
}

// 8x4x(K=16) tile from LDS a_s x register bank WB -> acc[8]
#define COMPUTE_ACC(WB)                                          \
  do {                                                           \
    _Pragma("unroll") for (int r = 0; r < 8; ++r) acc[r] =       \
        (f4){0.f, 0.f, 0.f, 0.f};                                \
    _Pragma("unroll") for (int q = 0; q < 4; ++q) {              \
      const f4 w0 = WB[4 * q], w1 = WB[4 * q + 1];               \
      const f4 w2 = WB[4 * q + 2], w3 = WB[4 * q + 3];           \
      const int ab = abase_k + 4 * q;                            \
      _Pragma("unroll") for (int r = 0; r < 8; ++r) {            \
        f4 a = *(const f4*)&a_s[r * APITCH + ab];                \
        acc[r] += a.x * w0 + a.y * w1 + a.z * w2 + a.w * w3;     \
      }                                                          \
    }                                                            \
  } while (0)

// ---------------- init: zero flags ----------------
__global__ void k_init(unsigned* __restrict__ flags) {
  int tid = blockIdx.x * 256 + threadIdx.x;
  if (tid < 512) flags[tid] = 0u;
}

// ------- xproj[t*64+n][u] = emb[x[n][t]] @ w_x + b_in (R2/R3-proven) -------
__global__ __launch_bounds__(256) void k_xproj(
    const int* __restrict__ x, const float* __restrict__ emb,
    const float* __restrict__ w_x, const float* __restrict__ b_in,
    float* __restrict__ xp) {
  __shared__ float a_s[64][36];
  __shared__ float w_s[32][64];
  __shared__ int idxs[64];
  const int tid = threadIdx.x;
  const int m0 = blockIdx.x * 64;
  const int c0 = blockIdx.y * 64;
  if (tid < 64) {
    int m = m0 + tid;
    idxs[tid] = x[(m & 63) * T + (m >> 6)];  // x[n][t], row m = t*64+n
  }
  __syncthreads();
  const int rq = tid >> 4, cq = tid & 15;
  float acc[4][4] = {};
  for (int k0 = 0; k0 < E; k0 += 32) {
#pragma unroll
    for (int rep = 0; rep < 8; ++rep) {
      int e = rep * 256 + tid;
      int r = e >> 5, k = e & 31;
      a_s[r][k] = emb[(size_t)idxs[r] * E + k0 + k];
    }
#pragma unroll
    for (int rep = 0; rep < 2; ++rep) {
      int e = rep * 256 + tid;
      int kr = e >> 4, q = e & 15;
      *(float4*)&w_s[kr][4 * q] =
          *(const float4*)(w_x + (size_t)(k0 + kr) * U + c0 + 4 * q);
    }
    __syncthreads();
#pragma unroll
    for (int kc = 0; kc < 32; kc += 4) {
      float4 a4[4], w4[4];
#pragma unroll
      for (int i = 0; i < 4; ++i) a4[i] = *(const float4*)&a_s[4 * rq + i][kc];
#pragma unroll
      for (int kk = 0; kk < 4; ++kk)
        w4[kk] = *(const float4*)&w_s[kc + kk][4 * cq];
#pragma unroll
      for (int i = 0; i < 4; ++i) {
        const float av[4] = {a4[i].x, a4[i].y, a4[i].z, a4[i].w};
#pragma unroll
        for (int kk = 0; kk < 4; ++kk) {
          acc[i][0] += av[kk] * w4[kk].x;
          acc[i][1] += av[kk] * w4[kk].y;
          acc[i][2] += av[kk] * w4[kk].z;
          acc[i][3] += av[kk] * w4[kk].w;
        }
      }
    }
    __syncthreads();
  }
  const float4 bb = *(const float4*)(b_in + c0 + 4 * cq);
  const float bv[4] = {bb.x, bb.y, bb.z, bb.w};
#pragma unroll
  for (int i = 0; i < 4; ++i) {
    float4 o;
    o.x = acc[i][0] + bv[0];
    o.y = acc[i][1] + bv[1];
    o.z = acc[i][2] + bv[2];
    o.w = acc[i][3] + bv[3];
    *(float4*)(xp + (size_t)(m0 + 4 * rq + i) * U + c0 + 4 * cq) = o;
  }
}

// ---------------- sequential pipeline ----------------
// 256 WGs. cg = (bid&7)*4 + ((bid>>3)&3), rg = bid>>5 (R11 mapping).
// Thread (s',ci): K-slice [16s',16s'+16), ALL 8 rows, cols [4ci,4ci+4) of 32.
// Phase Q=1..3T: j=(Q-1)%3 -> j0: h2=lrelu(h1@Wh0+b0); j1: h3=lrelu(h2@Wh1+b1);
// j2: u += h3@W2 + c2, store h1'=lrelu(u+xp[t+1]); off-chain y += h3@w_out.
__global__ __launch_bounds__(512, 2) void k_seq(
    const float* __restrict__ xp, const float* __restrict__ w_y,
    const float* __restrict__ w_h, const float* __restrict__ b_h,
    const float* __restrict__ w_out, const float* __restrict__ b_out,
    const float* __restrict__ h0, float* __restrict__ out,
    float* __restrict__ slots, unsigned* __restrict__ flags) {
  __shared__ float a_s[8 * APITCH];    // 9248 floats
  __shared__ float red2[64 * RPITCH];  // 16896 floats
  __shared__ float c2_s[32], u0_s[32];
  const int tid = threadIdx.x;
  const int bid = blockIdx.x;
  const int cg = ((bid & 7) << 2) | ((bid >> 3) & 3);  // XCD-affine W slab
  const int rg = bid >> 5;
  const int w = tid >> 6, l = tid & 63;
  const int ci = l & 7;
  const int sp = w * 8 + (l >> 3);  // s' in [0,64)
  const int cb = 4 * ci, k0 = 16 * sp;
  const int abase_k = 36 * (sp >> 1) + 16 * (sp & 1);  // skewed k0 offset
  // finalize-lane coords (valid for tid < 256)
  const int frow = 8 * rg + (tid >> 5);
  const int fu = 32 * cg + (tid & 31);
  // staging coords: row set {tb, tb+2, tb+4, tb+6}, rotated k start
  const int tb = tid >> 8;                      // 0 or 1
  const int kq = ((tid & 255) + 8 * cg) & 255;  // f4-unit index, cg-rotated
  const int lofs = 36 * (kq >> 3) + ((4 * kq) & 31);  // skewed LDS k-offset

  // ============ PROLOGUE: w2reg = per-thread fragment of W2 = w_out@w_y,
  // c2 = b_out@w_y, u0 = h0@w_y (cols 32cg..+32). Redundant per WG; LDS
  // staging aliases red2 (w_out_s[1024][9]) and a_s (wy_s[8][36]). ~130us.
  float* const wos = red2;  // [1024][WOPITCH]
  float* const wys = a_s;   // [8][36]
  f4 w2reg[16];
#pragma unroll
  for (int jj = 0; jj < 16; ++jj) w2reg[jj] = (f4){0.f, 0.f, 0.f, 0.f};
  f4 c2a = (f4){0.f, 0.f, 0.f, 0.f}, u0a = (f4){0.f, 0.f, 0.f, 0.f};
  {
    // reg double-buffer for w_out rows (tid, tid+512) x 8 m-cols
    f4 nx0, nx1, nx2, nx3, nwy;
    {
      const float* wo = w_out + (size_t)tid * U;
      nx0 = *(const f4*)wo;
      nx1 = *(const f4*)(wo + 4);
      const float* wo2 = w_out + (size_t)(tid + 512) * U;
      nx2 = *(const f4*)wo2;
      nx3 = *(const f4*)(wo2 + 4);
      if (tid < 64)
        nwy = *(const f4*)(w_y + (size_t)(tid >> 3) * U + 32 * cg +
                           4 * (tid & 7));
    }
    for (int mi = 0; mi < 128; ++mi) {
      const int m0 = mi * 8;
      // LDS write current chunk
#pragma unroll
      for (int q = 0; q < 4; ++q) {
        wos[tid * WOPITCH + q] = nx0[q];
        wos[tid * WOPITCH + 4 + q] = nx1[q];
        wos[(tid + 512) * WOPITCH + q] = nx2[q];
        wos[(tid + 512) * WOPITCH + 4 + q] = nx3[q];
      }
      if (tid < 64) *(f4*)&wys[(tid >> 3) * 36 + 4 * (tid & 7)] = nwy;
      __syncthreads();
      // issue next chunk loads (latency hides under compute)
      if (mi < 127) {
        const int m1 = m0 + 8;
        const float* wo = w_out + (size_t)tid * U + m1;
        nx0 = *(const f4*)wo;
        nx1 = *(const f4*)(wo + 4);
        const float* wo2 = w_out + (size_t)(tid + 512) * U + m1;
        nx2 = *(const f4*)wo2;
        nx3 = *(const f4*)(wo2 + 4);
        if (tid < 64)
          nwy = *(const f4*)(w_y + (size_t)(m1 + (tid >> 3)) * U + 32 * cg +
                             4 * (tid & 7));
      }
#pragma unroll
      for (int mm = 0; mm < 8; ++mm) {
        const f4 wy = *(const f4*)&wys[mm * 36 + cb];
#pragma unroll
        for (int jj = 0; jj < 16; ++jj)
          w2reg[jj] += wos[(16 * sp + jj) * WOPITCH + mm] * wy;
        if (tid < 8) {  // sp==0 lanes: c2/u0 accumulation
          c2a += b_out[m0 + mm] * wy;
          u0a += h0[m0 + mm] * wy;
        }
      }
      __syncthreads();
    }
  }
  if (tid < 8) {
    *(f4*)&c2_s[cb] = c2a;
    *(f4*)&u0_s[cb] = u0a;
  }
  __syncthreads();
  // bootstrap: u,y registers; h1_0 -> slot0; release (post=1)
  float u_reg = 0.f, y_reg = 0.f, c2_lane = 0.f;
  if (tid < 256) {
    c2_lane = c2_s[tid & 31];
    u_reg = u0_s[tid & 31];
    y_reg = h0[fu];
    float h1 = LRELU(u_reg + xp[(size_t)frow * U + fu]);  // t=0
    llc_store(slots + (size_t)frow * U + fu, h1);         // slot0
  }
  asm volatile("" ::: "memory");
  __builtin_amdgcn_s_waitcnt(0);
  __syncthreads();
  if (tid == 0) llc_post(&flags[rg * 32 + cg], 1u);

  // W prefetch for Q=1 (Wh0)
  f4 wreg[16];
  {
    const float* wp = w_h + (size_t)k0 * U + 32 * cg + cb;
#pragma unroll
    for (int jj = 0; jj < 16; ++jj) wreg[jj] = *(const f4*)(wp + (size_t)jj * U);
  }

  // ============ MAIN LOOP: 3 phases per step ============
  for (int Q = 1; Q <= 3 * T; ++Q) {
    const int j = (Q - 1) % 3, t = (Q - 1) / 3;
    const float* Asrc =
        slots + (size_t)((Q + 1) & 1) * BU + (size_t)(8 * rg) * U;
    float* slotw = slots + (size_t)(Q & 1) * BU;
    // ---- 1. poll: wave0 vector-reads all 32 per-producer flags ----
    if (tid < 64) {
      const unsigned tgt = (unsigned)Q;
      const unsigned* fp = &flags[rg * 32 + (l & 31)];
      while (!__all(llc_flag(fp) >= tgt)) __builtin_amdgcn_s_sleep(1);
    }
    __syncthreads();
    asm volatile("" ::: "memory");
    // ---- 1b. finalize-operand prefetch (off the producer tail) ----
    float preA = 0.f, preB = 0.f;
    if (tid < 256) {
      if (j == 0)
        preA = b_h[fu];
      else if (j == 1)
        preA = b_h[U + fu];
      else {
        if (t < T - 1) preA = xp[((size_t)(t + 1) * B + frow) * U + fu];
        preB = b_out[fu];
      }
    }
    // ---- 2. stage A: 8 rows x 1024 floats, b128 sc1 loads, cg-rotated ----
    {
      const float* pb = Asrc + 4 * kq;
      f4 av0, av1, av2, av3;
      asm volatile("global_load_dwordx4 %0, %1, off sc1"
                   : "=v"(av0)
                   : "v"(pb + (size_t)tb * U));
      asm volatile("global_load_dwordx4 %0, %1, off sc1"
                   : "=v"(av1)
                   : "v"(pb + (size_t)(tb + 2) * U));
      asm volatile("global_load_dwordx4 %0, %1, off sc1"
                   : "=v"(av2)
                   : "v"(pb + (size_t)(tb + 4) * U));
      asm volatile("global_load_dwordx4 %0, %1, off sc1"
                   : "=v"(av3)
                   : "v"(pb + (size_t)(tb + 6) * U));
      asm volatile("s_waitcnt vmcnt(0)" ::: "memory");
      *(f4*)&a_s[(tb + 0) * APITCH + lofs] = av0;
      *(f4*)&a_s[(tb + 2) * APITCH + lofs] = av1;
      *(f4*)&a_s[(tb + 4) * APITCH + lofs] = av2;
      *(f4*)&a_s[(tb + 6) * APITCH + lofs] = av3;
    }
    __syncthreads();
    // ---- 3. on-chain matmul: Wh0/Wh1 from wreg, W2 from persistent regs ----
    f4 acc[8];
    if (j == 2)
      COMPUTE_ACC(w2reg);
    else
      COMPUTE_ACC(wreg);
#pragma unroll
    for (int r = 0; r < 8; ++r)
      *(f4*)&red2[sp * RPITCH + r * 32 + cb] = acc[r];
    __syncthreads();
    // ---- 4. finalize: sum 64 partials, update state, store exchange ----
    if (tid < 256) {
      float s0 = 0.f, s1 = 0.f, s2 = 0.f, s3 = 0.f;
#pragma unroll
      for (int z = 0; z < 64; z += 4) {
        s0 += red2[(z + 0) * RPITCH + tid];
        s1 += red2[(z + 1) * RPITCH + tid];
        s2 += red2[(z + 2) * RPITCH + tid];
        s3 += red2[(z + 3) * RPITCH + tid];
      }
      const float sum = (s0 + s1) + (s2 + s3);
      const size_t yi = (size_t)frow * U + fu;
      if (j < 2) {
        llc_store(slotw + yi, LRELU(sum + preA));  // h2 / h3
      } else {
        u_reg += sum + c2_lane;                    // u_{t+1}
        llc_store(slotw + yi, LRELU(u_reg + preA));  // h1_{t+1}
      }
    }
    // ---- 5. drain + release ----
    asm volatile("" ::: "memory");
    __builtin_amdgcn_s_waitcnt(0);
    __syncthreads();
    if (tid == 0) llc_post(&flags[rg * 32 + cg], (unsigned)(Q + 1));
    // ---- 6. j==2 OFF-CHAIN: y += h3@w_out + b_out; out[:,t,:] = y ----
    if (j == 2) {
      f4 acc2[8];
      {
        f4* acc = acc2;  // reuse macro
        if (true) COMPUTE_ACC(wreg);  // wreg holds w_out here
      }
#pragma unroll
      for (int r = 0; r < 8; ++r)
        *(f4*)&red2[sp * RPITCH + r * 32 + cb] = acc2[r];
      __syncthreads();
      if (tid < 256) {
        float s0 = 0.f, s1 = 0.f, s2 = 0.f, s3 = 0.f;
#pragma unroll
        for (int z = 0; z < 64; z += 4) {
          s0 += red2[(z + 0) * RPITCH + tid];
          s1 += red2[(z + 1) * RPITCH + tid];
          s2 += red2[(z + 2) * RPITCH + tid];
          s3 += red2[(z + 3) * RPITCH + tid];
        }
        y_reg += (s0 + s1) + (s2 + s3) + preB;
        out[((size_t)frow * T + t) * U + fu] = y_reg;
      }
    }
    // ---- 7. W prefetch for next phase: j0->Wh1, j1->w_out, j2->Wh0 ----
    if (Q < 3 * T) {
      const float* Wn = (j == 0) ? (w_h + (size_t)U * U)
                       : (j == 1) ? w_out
                                  : w_h;
      const float* wp = Wn + (size_t)k0 * U + 32 * cg + cb;
#pragma unroll
      for (int jj = 0; jj < 16; ++jj)
        wreg[jj] = *(const f4*)(wp + (size_t)jj * U);
    }
  }
}

extern "C" void kernel_launch(void* const* d_in, const int* in_sizes, int n_in,
                              void* d_out, int out_size, void* d_ws,
                              size_t ws_size, hipStream_t stream) {
  const int* x = (const int*)d_in[0];
  const float* emb = (const float*)d_in[1];
  const float* w_y = (const float*)d_in[2];
  const float* w_x = (const float*)d_in[3];
  const float* b_in = (const float*)d_in[4];
  const float* w_h = (const float*)d_in[5];
  const float* b_h = (const float*)d_in[6];
  const float* w_out = (const float*)d_in[7];
  const float* b_out = (const float*)d_in[8];
  const float* h0 = (const float*)d_in[9];
  float* out = (float*)d_out;

  // workspace (floats): xproj | slots[2] | (dead ybuf slot) | flags
  // layout IDENTICAL to R11 — footprint unchanged (R10 lesson).
  float* ws = (float*)d_ws;
  float* xpb = ws;                         // T*B*U
  float* slots = xpb + (size_t)T * B * U;  // 2*BU
  float* ybuf_dead = slots + 2 * (size_t)BU;         // BU (unused)
  unsigned* flags = (unsigned*)(ybuf_dead + (size_t)BU);  // 512 uints

  k_init<<<2, 256, 0, stream>>>(flags);
  dim3 g1(256, 16);
  k_xproj<<<g1, 256, 0, stream>>>(x, emb, w_x, b_in, xpb);

  void* args[] = {&xpb,  &w_y,   &w_h, &b_h,   &w_out,
                  &b_out, &h0,   &out, &slots, &flags};
  hipLaunchCooperativeKernel((void*)k_seq, dim3(256), dim3(512), args, 0u,
                             stream);
}